// Round 1
// baseline (2151.688 us; speedup 1.0000x reference)
//
#include <hip/hip_runtime.h>

#define BB 8
#define CC 128
#define NN 4096
#define MM 1024
#define TN 16
#define SQS 132      // float stride for 16x128 q/z tile (pad: bank-conflict-free, 16B aligned)
#define SCSB 1040    // ushort stride for 16x1024 bf16 score tile (16B-aligned rows)

static __device__ __forceinline__ unsigned short f2b(float f) {
    unsigned int u = __float_as_uint(f);
    u += 0x7fffu + ((u >> 16) & 1u);        // round-to-nearest-even
    return (unsigned short)(u >> 16);
}

// Kernel 1: K = y_flat @ Wk^T + bk ; V = y_flat @ Wv^T + bv   (fp32 -> ws)
__global__ __launch_bounds__(128) void kv_proj(
    const float* __restrict__ y, const float* __restrict__ Wk,
    const float* __restrict__ bk, const float* __restrict__ Wv,
    const float* __restrict__ bv, float* __restrict__ K, float* __restrict__ V)
{
    __shared__ __align__(16) float sy[CC];
    const int tid = threadIdx.x;
    const int bm = blockIdx.x;
    const int b = bm >> 10, m = bm & (MM - 1);
    // y layout: [B][C][M]; token m's channel vector is strided by M
    sy[tid] = y[(size_t)b * CC * MM + (size_t)tid * MM + m];
    __syncthreads();
    const float4* wk4 = (const float4*)(Wk + tid * CC);
    const float4* wv4 = (const float4*)(Wv + tid * CC);
    const float4* sy4 = (const float4*)sy;
    float aK = bk[tid], aV = bv[tid];
#pragma unroll
    for (int i = 0; i < CC / 4; ++i) {
        float4 yv = sy4[i];
        float4 k = wk4[i], v = wv4[i];
        aK += yv.x * k.x + yv.y * k.y + yv.z * k.z + yv.w * k.w;
        aV += yv.x * v.x + yv.y * v.y + yv.z * v.z + yv.w * v.w;
    }
    K[(size_t)bm * CC + tid] = aK;
    V[(size_t)bm * CC + tid] = aV;
}

// Kernel 2: fused Q-proj + scores + softmax + PV + residual. One block = 16 q-tokens.
__global__ __launch_bounds__(256) void attn(
    const float* __restrict__ x, const float* __restrict__ Wq,
    const float* __restrict__ bq, const float* __restrict__ K,
    const float* __restrict__ V, float* __restrict__ out)
{
    __shared__ __align__(16) char smem[TN * SCSB * 2];   // 33280 B: x-tile then bf16 scores
    __shared__ __align__(16) float sq[TN * SQS];         // q tile, later z tile
    __shared__ float red[TN];                            // 1/rowsum

    float* sx = (float*)smem;              // [CC][TN], dead after Q-proj
    unsigned short* scb = (unsigned short*)smem;  // [TN][SCSB] bf16 scores/weights

    const int tid = threadIdx.x;
    const int b  = blockIdx.x >> 8;             // 256 n-tiles per batch
    const int n0 = (blockIdx.x & 255) * TN;
    const float scale = 0.0883883476483184f;    // 1/sqrt(128)

    // ---- Phase A: load x tile (coalesced 64B segments per 16 lanes) ----
    {
        const int tn = tid & 15, c0 = tid >> 4;
#pragma unroll
        for (int k = 0; k < 8; ++k) {
            const int c = c0 + 16 * k;
            sx[c * TN + tn] = x[(size_t)b * CC * NN + (size_t)c * NN + n0 + tn];
        }
    }
    __syncthreads();

    // ---- Phase B: Q projection -> sq[tn][d] ----
    {
        const int d = tid & 127, tng = tid >> 7;   // 8 tn per thread
        float acc[8];
        const float bias = bq[d];
#pragma unroll
        for (int t = 0; t < 8; ++t) acc[t] = bias;
        const float4* wrow4 = (const float4*)(Wq + d * CC);
        for (int c4 = 0; c4 < CC / 4; ++c4) {
            const float4 w = wrow4[c4];
#pragma unroll
            for (int i = 0; i < 4; ++i) {
                const int c = c4 * 4 + i;
                const float wc = (i == 0) ? w.x : (i == 1) ? w.y : (i == 2) ? w.z : w.w;
                const float4* sxt = (const float4*)(sx + c * TN + tng * 8);
                float4 a0 = sxt[0], a1 = sxt[1];
                acc[0] += wc * a0.x; acc[1] += wc * a0.y; acc[2] += wc * a0.z; acc[3] += wc * a0.w;
                acc[4] += wc * a1.x; acc[5] += wc * a1.y; acc[6] += wc * a1.z; acc[7] += wc * a1.w;
            }
        }
#pragma unroll
        for (int t = 0; t < 8; ++t) sq[(tng * 8 + t) * SQS + d] = acc[t];
    }
    __syncthreads();   // sx dead beyond this point; scb takes over smem

    // ---- Phase C: scores S[tn][m] = q . K[m] * scale, rowmax tracked ----
    const int tn = tid >> 4, g = tid & 15;   // row tn handled by 16 contiguous lanes
    float rowmax = -1e30f;
    {
        const float4* q4 = (const float4*)(sq + tn * SQS);
        const float* kb = K + (size_t)b * MM * CC;
        for (int jc = 0; jc < 8; ++jc) {     // 8 chunks x 8 rows = 64 m per thread
            float s[8] = {0.f,0.f,0.f,0.f,0.f,0.f,0.f,0.f};
            const float4* kr[8];
#pragma unroll
            for (int t = 0; t < 8; ++t)
                kr[t] = (const float4*)(kb + (size_t)(g + 16 * (jc * 8 + t)) * CC);
#pragma unroll 4
            for (int c4 = 0; c4 < CC / 4; ++c4) {
                const float4 q = q4[c4];
#pragma unroll
                for (int t = 0; t < 8; ++t) {
                    const float4 kk = kr[t][c4];
                    s[t] += q.x * kk.x + q.y * kk.y + q.z * kk.z + q.w * kk.w;
                }
            }
#pragma unroll
            for (int t = 0; t < 8; ++t) {
                const float sv = s[t] * scale;
                scb[tn * SCSB + g + 16 * (jc * 8 + t)] = f2b(sv);
                rowmax = fmaxf(rowmax, sv);
            }
        }
    }
    // rowwise max across the 16 lanes of this row (lanes contiguous in-wave)
#pragma unroll
    for (int off = 1; off < 16; off <<= 1)
        rowmax = fmaxf(rowmax, __shfl_xor(rowmax, off));

    // ---- exp pass: in-place, accumulate row sum (reads own writes; no barrier) ----
    float rowsum = 0.f;
    for (int j = 0; j < 64; ++j) {
        const int idx = tn * SCSB + g + 16 * j;
        const float s = __uint_as_float(((unsigned int)scb[idx]) << 16);
        const float e = __expf(s - rowmax);
        scb[idx] = f2b(e);
        rowsum += e;
    }
#pragma unroll
    for (int off = 1; off < 16; off <<= 1)
        rowsum += __shfl_xor(rowsum, off);
    if (g == 0) red[tn] = 1.0f / rowsum;
    __syncthreads();

    // ---- Phase D: z[tn][d] = sum_m w[tn][m] * V[m][d] ----
    {
        const int d0 = tid & 63, tng = tid >> 6;    // 4 tn x 2 d per thread
        float z[8] = {0.f,0.f,0.f,0.f,0.f,0.f,0.f,0.f};
        const float* vb = V + (size_t)b * MM * CC;
        for (int m = 0; m < MM; m += 8) {
            float va[8], vc[8];
#pragma unroll
            for (int i = 0; i < 8; ++i) {
                va[i] = vb[(size_t)(m + i) * CC + d0];        // coalesced across lanes
                vc[i] = vb[(size_t)(m + i) * CC + d0 + 64];
            }
#pragma unroll
            for (int t = 0; t < 4; ++t) {
                // 8 bf16 weights, wave-uniform broadcast read
                const uint4 wp = *(const uint4*)(scb + (tng * 4 + t) * SCSB + m);
                const unsigned int uw[4] = {wp.x, wp.y, wp.z, wp.w};
#pragma unroll
                for (int i = 0; i < 4; ++i) {
                    const float wlo = __uint_as_float(uw[i] << 16);
                    const float whi = __uint_as_float(uw[i] & 0xffff0000u);
                    z[t]     += wlo * va[2 * i] + whi * va[2 * i + 1];
                    z[t + 4] += wlo * vc[2 * i] + whi * vc[2 * i + 1];
                }
            }
        }
#pragma unroll
        for (int t = 0; t < 4; ++t) {
            const float r = red[tng * 4 + t];
            sq[(tng * 4 + t) * SQS + d0]      = z[t] * r;      // reuse sq as z tile
            sq[(tng * 4 + t) * SQS + d0 + 64] = z[t + 4] * r;
        }
    }
    __syncthreads();

    // ---- Epilogue: out = x + z, coalesced 64B segments ----
    {
        const int tnr = tid & 15, c0 = tid >> 4;
#pragma unroll
        for (int k = 0; k < 8; ++k) {
            const int c = c0 + 16 * k;
            const size_t gi = (size_t)b * CC * NN + (size_t)c * NN + n0 + tnr;
            out[gi] = x[gi] + sq[tnr * SQS + c];
        }
    }
}

extern "C" void kernel_launch(void* const* d_in, const int* in_sizes, int n_in,
                              void* d_out, int out_size, void* d_ws, size_t ws_size,
                              hipStream_t stream) {
    const float* x  = (const float*)d_in[0];
    const float* y  = (const float*)d_in[1];
    const float* Wq = (const float*)d_in[2];
    const float* bq = (const float*)d_in[3];
    const float* Wk = (const float*)d_in[4];
    const float* bk = (const float*)d_in[5];
    const float* Wv = (const float*)d_in[6];
    const float* bv = (const float*)d_in[7];
    float* out = (float*)d_out;

    float* Kw = (float*)d_ws;                       // 8*1024*128 fp32 = 4 MB
    float* Vw = Kw + (size_t)BB * MM * CC;          // + 4 MB  (ws >= 8 MB)

    kv_proj<<<BB * MM, 128, 0, stream>>>(y, Wk, bk, Wv, bv, Kw, Vw);
    attn<<<BB * (NN / TN), 256, 0, stream>>>(x, Wq, bq, Kw, Vw, out);
}

// Round 2
// 185.837 us; speedup vs baseline: 11.5783x; 11.5783x over previous
//
#include <hip/hip_runtime.h>

#define BB 8
#define CCH 128
#define NN 4096
#define MMK 1024

typedef __bf16 v8bf __attribute__((ext_vector_type(8)));
typedef float v4f __attribute__((ext_vector_type(4)));
#define MFMA16 __builtin_amdgcn_mfma_f32_16x16x32_bf16

// ---------------- Kernel 1: all projections via MFMA ----------------
// jobs: blocks 0..255 -> Q (scaled), 256..319 -> K, 320..383 -> V(transposed out)
__global__ __launch_bounds__(256, 1) void proj(
    const float* __restrict__ x, const float* __restrict__ y,
    const float* __restrict__ Wq, const float* __restrict__ bq,
    const float* __restrict__ Wk, const float* __restrict__ bk,
    const float* __restrict__ Wv, const float* __restrict__ bv,
    __bf16* __restrict__ Qg, __bf16* __restrict__ Kg, __bf16* __restrict__ Vtg)
{
    __shared__ __align__(16) __bf16 xt[128 * 132];   // [c][tok], pad->132
    __shared__ float bsh[128];

    const int tid = threadIdx.x;
    const int wave = tid >> 6, lane = tid & 63, l15 = lane & 15, quad = lane >> 4;
    const int bid = blockIdx.x;

    int job, b, t0, stride;
    const float *in, *W, *bias;
    if (bid < 256)      { job = 0; b = bid >> 5;         t0 = (bid & 31) * 128;        in = x; stride = NN;  W = Wq; bias = bq; }
    else if (bid < 320) { job = 1; b = (bid - 256) >> 3; t0 = ((bid - 256) & 7) * 128; in = y; stride = MMK; W = Wk; bias = bk; }
    else                { job = 2; b = (bid - 320) >> 3; t0 = ((bid - 320) & 7) * 128; in = y; stride = MMK; W = Wv; bias = bv; }

    // stage input tile [128 c][128 tok] -> bf16 LDS (coalesced float4 reads)
    #pragma unroll
    for (int i = 0; i < 16; ++i) {
        const int s = i * 256 + tid;
        const int c = s >> 5, c4 = s & 31;
        float4 v = *(const float4*)(in + (size_t)(b * 128 + c) * stride + t0 + c4 * 4);
        union { __bf16 h[4]; uint2 u; } o;
        o.h[0] = (__bf16)v.x; o.h[1] = (__bf16)v.y; o.h[2] = (__bf16)v.z; o.h[3] = (__bf16)v.w;
        *(uint2*)(xt + c * 132 + c4 * 4) = o.u;
    }
    if (tid < 128) bsh[tid] = bias[tid];
    __syncthreads();

    // input B-frags: lane holds in[tok=l15+tg*16][c=cg*32+quad*8+j]
    v8bf xf[2][4];
    #pragma unroll
    for (int tg2 = 0; tg2 < 2; ++tg2) {
        const int tok = (wave * 2 + tg2) * 16 + l15;
        #pragma unroll
        for (int cg = 0; cg < 4; ++cg) {
            union { __bf16 h[8]; v8bf v; } u;
            #pragma unroll
            for (int jj = 0; jj < 8; ++jj)
                u.h[jj] = xt[(cg * 32 + quad * 8 + jj) * 132 + tok];
            xf[tg2][cg] = u.v;
        }
    }

    const float scale = (job == 0) ? 0.0883883476483184f : 1.0f;  // 1/sqrt(128)

    for (int dg = 0; dg < 8; ++dg) {
        // W A-frags: lane holds W[d=dg*16+l15][c=cg*32+quad*8+j]
        v8bf wf[4];
        #pragma unroll
        for (int cg = 0; cg < 4; ++cg) {
            const float* wp = W + (size_t)(dg * 16 + l15) * 128 + cg * 32 + quad * 8;
            float4 a = *(const float4*)wp;
            float4 c2 = *(const float4*)(wp + 4);
            union { __bf16 h[8]; v8bf v; } u;
            u.h[0] = (__bf16)a.x;  u.h[1] = (__bf16)a.y;  u.h[2] = (__bf16)a.z;  u.h[3] = (__bf16)a.w;
            u.h[4] = (__bf16)c2.x; u.h[5] = (__bf16)c2.y; u.h[6] = (__bf16)c2.z; u.h[7] = (__bf16)c2.w;
            wf[cg] = u.v;
        }
        float bz[4];
        #pragma unroll
        for (int r = 0; r < 4; ++r) bz[r] = bsh[dg * 16 + quad * 4 + r];

        #pragma unroll
        for (int tg2 = 0; tg2 < 2; ++tg2) {
            v4f acc;
            #pragma unroll
            for (int r = 0; r < 4; ++r) acc[r] = bz[r];
            #pragma unroll
            for (int cg = 0; cg < 4; ++cg)
                acc = MFMA16(wf[cg], xf[tg2][cg], acc, 0, 0, 0);
            #pragma unroll
            for (int r = 0; r < 4; ++r) acc[r] *= scale;

            const int tok = t0 + (wave * 2 + tg2) * 16 + l15;   // token within batch
            if (job <= 1) {
                // row-major [token][d] bf16
                __bf16* Out = (job == 0) ? Qg : Kg;
                const int ntok = (job == 0) ? NN : MMK;
                union { __bf16 h[4]; uint2 u; } o;
                #pragma unroll
                for (int r = 0; r < 4; ++r) o.h[r] = (__bf16)acc[r];
                *(uint2*)(Out + (size_t)(b * ntok + tok) * 128 + dg * 16 + quad * 4) = o.u;
            } else {
                // Vt [c][m] bf16
                #pragma unroll
                for (int r = 0; r < 4; ++r)
                    Vtg[(size_t)(b * 128 + dg * 16 + quad * 4 + r) * MMK + tok] = (__bf16)acc[r];
            }
        }
    }
}

// ---------------- Kernel 2: flash attention, MFMA ----------------
// 256 blocks (b = bid>>5, n0 = (bid&31)*128), 4 waves x 32 q-rows.
// LDS: Ks[64][136] bf16 (17408B) + Vts[128][72] bf16 (18432B) + P 8x[16][72] (18432B)
#define KS_STR 136
#define VT_STR 72
#define P_STR  72

__global__ __launch_bounds__(256, 1) void attn(
    const float* __restrict__ x, const __bf16* __restrict__ Qg,
    const __bf16* __restrict__ Kg, const __bf16* __restrict__ Vtg,
    float* __restrict__ out)
{
    __shared__ __align__(16) __bf16 smem[27136];
    __bf16* Ks  = smem;                    // 64*136 = 8704
    __bf16* Vts = smem + 8704;             // 128*72 = 9216
    __bf16* Pb  = smem + 8704 + 9216;      // 8 * 16*72 = 9216

    const int tid = threadIdx.x;
    const int wave = tid >> 6, lane = tid & 63, l15 = lane & 15, quad = lane >> 4;
    const int b = blockIdx.x >> 5;
    const int n0 = (blockIdx.x & 31) << 7;

    // Q B-frags (scaled at projection time): lane holds Q[qrow=l15][c=kk*32+quad*8+j]
    v8bf qf[2][4];
    #pragma unroll
    for (int rg = 0; rg < 2; ++rg) {
        const int row = n0 + wave * 32 + rg * 16 + l15;
        #pragma unroll
        for (int kk = 0; kk < 4; ++kk)
            qf[rg][kk] = *(const v8bf*)(Qg + ((size_t)(b * NN + row) * 128 + kk * 32 + quad * 8));
    }

    v4f of[2][8];
    #pragma unroll
    for (int rg = 0; rg < 2; ++rg)
        #pragma unroll
        for (int cg = 0; cg < 8; ++cg)
            #pragma unroll
            for (int r = 0; r < 4; ++r) of[rg][cg][r] = 0.f;
    float rm[2] = {-1e30f, -1e30f}, rl[2] = {0.f, 0.f};

    // stage chunk 0
    #pragma unroll
    for (int i = 0; i < 4; ++i) {
        const int s = i * 256 + tid, key = s >> 4, c16 = s & 15;
        *(uint4*)(Ks + key * KS_STR + c16 * 8) =
            *(const uint4*)(Kg + ((size_t)(b * MMK + key) * 128 + c16 * 8));
    }
    #pragma unroll
    for (int i = 0; i < 4; ++i) {
        const int s = i * 256 + tid, ch = s >> 3, kc = (s & 7) * 8;
        *(uint4*)(Vts + ch * VT_STR + kc) =
            *(const uint4*)(Vtg + ((size_t)(b * 128 + ch) * MMK + kc));
    }
    __syncthreads();

    __bf16* Pw0 = Pb + (wave * 2) * (16 * P_STR) + l15 * P_STR;
    __bf16* Pw1 = Pb + (wave * 2 + 1) * (16 * P_STR) + l15 * P_STR;

    for (int j = 0; j < 16; ++j) {
        // prefetch next chunk into registers
        uint4 pf[8];
        const int k0n = (j + 1) * 64;
        if (j < 15) {
            #pragma unroll
            for (int i = 0; i < 4; ++i) {
                const int s = i * 256 + tid, key = s >> 4, c16 = s & 15;
                pf[i] = *(const uint4*)(Kg + ((size_t)(b * MMK + k0n + key) * 128 + c16 * 8));
            }
            #pragma unroll
            for (int i = 0; i < 4; ++i) {
                const int s = i * 256 + tid, ch = s >> 3, kc = (s & 7) * 8;
                pf[4 + i] = *(const uint4*)(Vtg + ((size_t)(b * 128 + ch) * MMK + k0n + kc));
            }
        }

        // ---- S^T = K . Q^T : D[key][qrow], 64 keys x (2 x 16 qrows) ----
        v4f s[2][4];
        #pragma unroll
        for (int kg = 0; kg < 4; ++kg) {
            v8bf kf[4];
            #pragma unroll
            for (int kk = 0; kk < 4; ++kk)
                kf[kk] = *(const v8bf*)(Ks + (kg * 16 + l15) * KS_STR + kk * 32 + quad * 8);
            #pragma unroll
            for (int rg = 0; rg < 2; ++rg) {
                v4f a; a[0] = 0.f; a[1] = 0.f; a[2] = 0.f; a[3] = 0.f;
                #pragma unroll
                for (int kk = 0; kk < 4; ++kk)
                    a = MFMA16(kf[kk], qf[rg][kk], a, 0, 0, 0);
                s[rg][kg] = a;
            }
        }

        // ---- online softmax (per lane scalar state: qrow = l15) ----
        #pragma unroll
        for (int rg = 0; rg < 2; ++rg) {
            float cm = -1e30f;
            #pragma unroll
            for (int kg = 0; kg < 4; ++kg)
                #pragma unroll
                for (int r = 0; r < 4; ++r) cm = fmaxf(cm, s[rg][kg][r]);
            cm = fmaxf(cm, __shfl_xor(cm, 16));
            cm = fmaxf(cm, __shfl_xor(cm, 32));
            const float nm = fmaxf(rm[rg], cm);
            const float al = __expf(rm[rg] - nm);
            rm[rg] = nm;
            float cs = 0.f;
            #pragma unroll
            for (int kg = 0; kg < 4; ++kg)
                #pragma unroll
                for (int r = 0; r < 4; ++r) {
                    const float p = __expf(s[rg][kg][r] - nm);
                    s[rg][kg][r] = p; cs += p;
                }
            cs += __shfl_xor(cs, 16);
            cs += __shfl_xor(cs, 32);
            rl[rg] = rl[rg] * al + cs;
            #pragma unroll
            for (int cg = 0; cg < 8; ++cg)
                #pragma unroll
                for (int r = 0; r < 4; ++r) of[rg][cg][r] *= al;
            // write P[qrow][key] bf16 (4 consecutive keys packed -> 8B)
            __bf16* Pw = (rg == 0) ? Pw0 : Pw1;
            #pragma unroll
            for (int kg = 0; kg < 4; ++kg) {
                union { __bf16 h[4]; uint2 u; } pk;
                #pragma unroll
                for (int r = 0; r < 4; ++r) pk.h[r] = (__bf16)s[rg][kg][r];
                *(uint2*)(Pw + kg * 16 + quad * 4) = pk.u;
            }
        }

        // ---- O^T += Vt . P : D[ch][qrow] ----
        #pragma unroll
        for (int kg2 = 0; kg2 < 2; ++kg2) {
            v8bf pfr[2];
            pfr[0] = *(const v8bf*)(Pw0 + kg2 * 32 + quad * 8);
            pfr[1] = *(const v8bf*)(Pw1 + kg2 * 32 + quad * 8);
            #pragma unroll
            for (int cg = 0; cg < 8; ++cg) {
                v8bf vf = *(const v8bf*)(Vts + (cg * 16 + l15) * VT_STR + kg2 * 32 + quad * 8);
                of[0][cg] = MFMA16(vf, pfr[0], of[0][cg], 0, 0, 0);
                of[1][cg] = MFMA16(vf, pfr[1], of[1][cg], 0, 0, 0);
            }
        }

        // ---- stage next chunk ----
        if (j < 15) {
            __syncthreads();   // everyone done reading current chunk
            #pragma unroll
            for (int i = 0; i < 4; ++i) {
                const int s = i * 256 + tid, key = s >> 4, c16 = s & 15;
                *(uint4*)(Ks + key * KS_STR + c16 * 8) = pf[i];
            }
            #pragma unroll
            for (int i = 0; i < 4; ++i) {
                const int s = i * 256 + tid, ch = s >> 3, kc = (s & 7) * 8;
                *(uint4*)(Vts + ch * VT_STR + kc) = pf[4 + i];
            }
            __syncthreads();
        }
    }

    // ---- epilogue: out = x + O/l ----
    #pragma unroll
    for (int rg = 0; rg < 2; ++rg) {
        const float inv = 1.0f / rl[rg];
        const int n = n0 + wave * 32 + rg * 16 + l15;
        #pragma unroll
        for (int cg = 0; cg < 8; ++cg)
            #pragma unroll
            for (int r = 0; r < 4; ++r) {
                const int ch = cg * 16 + quad * 4 + r;
                const size_t gi = (size_t)(b * 128 + ch) * NN + n;
                out[gi] = x[gi] + of[rg][cg][r] * inv;
            }
    }
}

extern "C" void kernel_launch(void* const* d_in, const int* in_sizes, int n_in,
                              void* d_out, int out_size, void* d_ws, size_t ws_size,
                              hipStream_t stream) {
    const float* x  = (const float*)d_in[0];
    const float* y  = (const float*)d_in[1];
    const float* Wq = (const float*)d_in[2];
    const float* bq = (const float*)d_in[3];
    const float* Wk = (const float*)d_in[4];
    const float* bk = (const float*)d_in[5];
    const float* Wv = (const float*)d_in[6];
    const float* bv = (const float*)d_in[7];
    float* out = (float*)d_out;

    __bf16* Qg  = (__bf16*)d_ws;                        // 8*4096*128 = 8 MB
    __bf16* Kg  = Qg + (size_t)BB * NN * CCH;           // 2 MB
    __bf16* Vtg = Kg + (size_t)BB * MMK * CCH;          // 2 MB

    proj<<<384, 256, 0, stream>>>(x, y, Wq, bq, Wk, bk, Wv, bv, Qg, Kg, Vtg);
    attn<<<BB * (NN / 128), 256, 0, stream>>>(x, Qg, Kg, Vtg, out);
}

// Round 3
// 182.109 us; speedup vs baseline: 11.8154x; 1.0205x over previous
//
#include <hip/hip_runtime.h>

#define BB 8
#define CCH 128
#define NN 4096
#define MMK 1024

typedef __bf16 v8bf __attribute__((ext_vector_type(8)));
typedef float v4f __attribute__((ext_vector_type(4)));
#define MFMA16 __builtin_amdgcn_mfma_f32_16x16x32_bf16

// ---------------- Kernel 1: all projections via MFMA ----------------
// jobs: blocks 0..255 -> Q (scaled), 256..319 -> K, 320..383 -> V(transposed out)
__global__ __launch_bounds__(256, 1) void proj(
    const float* __restrict__ x, const float* __restrict__ y,
    const float* __restrict__ Wq, const float* __restrict__ bq,
    const float* __restrict__ Wk, const float* __restrict__ bk,
    const float* __restrict__ Wv, const float* __restrict__ bv,
    __bf16* __restrict__ Qg, __bf16* __restrict__ Kg, __bf16* __restrict__ Vtg)
{
    __shared__ __align__(16) __bf16 xt[128 * 132];   // [c][tok], pad->132
    __shared__ float bsh[128];

    const int tid = threadIdx.x;
    const int wave = tid >> 6, lane = tid & 63, l15 = lane & 15, quad = lane >> 4;
    const int bid = blockIdx.x;

    int job, b, t0, stride;
    const float *in, *W, *bias;
    if (bid < 256)      { job = 0; b = bid >> 5;         t0 = (bid & 31) * 128;        in = x; stride = NN;  W = Wq; bias = bq; }
    else if (bid < 320) { job = 1; b = (bid - 256) >> 3; t0 = ((bid - 256) & 7) * 128; in = y; stride = MMK; W = Wk; bias = bk; }
    else                { job = 2; b = (bid - 320) >> 3; t0 = ((bid - 320) & 7) * 128; in = y; stride = MMK; W = Wv; bias = bv; }

    #pragma unroll
    for (int i = 0; i < 16; ++i) {
        const int s = i * 256 + tid;
        const int c = s >> 5, c4 = s & 31;
        float4 v = *(const float4*)(in + (size_t)(b * 128 + c) * stride + t0 + c4 * 4);
        union { __bf16 h[4]; uint2 u; } o;
        o.h[0] = (__bf16)v.x; o.h[1] = (__bf16)v.y; o.h[2] = (__bf16)v.z; o.h[3] = (__bf16)v.w;
        *(uint2*)(xt + c * 132 + c4 * 4) = o.u;
    }
    if (tid < 128) bsh[tid] = bias[tid];
    __syncthreads();

    v8bf xf[2][4];
    #pragma unroll
    for (int tg2 = 0; tg2 < 2; ++tg2) {
        const int tok = (wave * 2 + tg2) * 16 + l15;
        #pragma unroll
        for (int cg = 0; cg < 4; ++cg) {
            union { __bf16 h[8]; v8bf v; } u;
            #pragma unroll
            for (int jj = 0; jj < 8; ++jj)
                u.h[jj] = xt[(cg * 32 + quad * 8 + jj) * 132 + tok];
            xf[tg2][cg] = u.v;
        }
    }

    const float scale = (job == 0) ? 0.0883883476483184f : 1.0f;  // 1/sqrt(128)

    for (int dg = 0; dg < 8; ++dg) {
        v8bf wf[4];
        #pragma unroll
        for (int cg = 0; cg < 4; ++cg) {
            const float* wp = W + (size_t)(dg * 16 + l15) * 128 + cg * 32 + quad * 8;
            float4 a = *(const float4*)wp;
            float4 c2 = *(const float4*)(wp + 4);
            union { __bf16 h[8]; v8bf v; } u;
            u.h[0] = (__bf16)a.x;  u.h[1] = (__bf16)a.y;  u.h[2] = (__bf16)a.z;  u.h[3] = (__bf16)a.w;
            u.h[4] = (__bf16)c2.x; u.h[5] = (__bf16)c2.y; u.h[6] = (__bf16)c2.z; u.h[7] = (__bf16)c2.w;
            wf[cg] = u.v;
        }
        float bz[4];
        #pragma unroll
        for (int r = 0; r < 4; ++r) bz[r] = bsh[dg * 16 + quad * 4 + r];

        #pragma unroll
        for (int tg2 = 0; tg2 < 2; ++tg2) {
            v4f acc;
            #pragma unroll
            for (int r = 0; r < 4; ++r) acc[r] = bz[r];
            #pragma unroll
            for (int cg = 0; cg < 4; ++cg)
                acc = MFMA16(wf[cg], xf[tg2][cg], acc, 0, 0, 0);
            #pragma unroll
            for (int r = 0; r < 4; ++r) acc[r] *= scale;

            const int tok = t0 + (wave * 2 + tg2) * 16 + l15;
            if (job <= 1) {
                __bf16* Out = (job == 0) ? Qg : Kg;
                const int ntok = (job == 0) ? NN : MMK;
                union { __bf16 h[4]; uint2 u; } o;
                #pragma unroll
                for (int r = 0; r < 4; ++r) o.h[r] = (__bf16)acc[r];
                *(uint2*)(Out + (size_t)(b * ntok + tok) * 128 + dg * 16 + quad * 4) = o.u;
            } else {
                #pragma unroll
                for (int r = 0; r < 4; ++r)
                    Vtg[(size_t)(b * 128 + dg * 16 + quad * 4 + r) * MMK + tok] = (__bf16)acc[r];
            }
        }
    }
}

// ---------------- Kernel 2: flash attention, MFMA ----------------
// 512 blocks (2/CU): b = bid>>6, n0 = (bid&63)*64. 4 waves x 16 q-rows.
// LDS: Ks[64][136] (17408B) + Vts[128][72] (18432B) + P 4x[16][72] (9216B) = 45056B
#define KS_STR 136
#define VT_STR 72
#define P_STR  72

__global__ __launch_bounds__(256, 2) void attn(
    const float* __restrict__ x, const __bf16* __restrict__ Qg,
    const __bf16* __restrict__ Kg, const __bf16* __restrict__ Vtg,
    float* __restrict__ out)
{
    __shared__ __align__(16) __bf16 smem[22528];
    __bf16* Ks  = smem;                    // 64*136 = 8704
    __bf16* Vts = smem + 8704;             // 128*72 = 9216
    __bf16* Pb  = smem + 8704 + 9216;      // 4 * 16*72 = 4608

    const int tid = threadIdx.x;
    const int wave = tid >> 6, lane = tid & 63, l15 = lane & 15, quad = lane >> 4;
    const int b = blockIdx.x >> 6;
    const int n0 = (blockIdx.x & 63) << 6;

    // Q B-frag (pre-scaled): lane holds Q[qrow=l15][c=kk*32+quad*8+j]
    v8bf qf[4];
    {
        const int row = n0 + wave * 16 + l15;
        #pragma unroll
        for (int kk = 0; kk < 4; ++kk)
            qf[kk] = *(const v8bf*)(Qg + ((size_t)(b * NN + row) * 128 + kk * 32 + quad * 8));
    }

    v4f of[8];
    #pragma unroll
    for (int cg = 0; cg < 8; ++cg)
        #pragma unroll
        for (int r = 0; r < 4; ++r) of[cg][r] = 0.f;
    float rm = -1e30f, rl = 0.f;

    // stage chunk 0
    #pragma unroll
    for (int i = 0; i < 4; ++i) {
        const int s = i * 256 + tid, key = s >> 4, c16 = s & 15;
        *(uint4*)(Ks + key * KS_STR + c16 * 8) =
            *(const uint4*)(Kg + ((size_t)(b * MMK + key) * 128 + c16 * 8));
    }
    #pragma unroll
    for (int i = 0; i < 4; ++i) {
        const int s = i * 256 + tid, ch = s >> 3, kc = (s & 7) * 8;
        *(uint4*)(Vts + ch * VT_STR + kc) =
            *(const uint4*)(Vtg + ((size_t)(b * 128 + ch) * MMK + kc));
    }
    __syncthreads();

    __bf16* Pw = Pb + wave * (16 * P_STR) + l15 * P_STR;

    for (int j = 0; j < 16; ++j) {
        // register prefetch of next chunk
        uint4 pf[8];
        const int k0n = (j + 1) * 64;
        if (j < 15) {
            #pragma unroll
            for (int i = 0; i < 4; ++i) {
                const int s = i * 256 + tid, key = s >> 4, c16 = s & 15;
                pf[i] = *(const uint4*)(Kg + ((size_t)(b * MMK + k0n + key) * 128 + c16 * 8));
            }
            #pragma unroll
            for (int i = 0; i < 4; ++i) {
                const int s = i * 256 + tid, ch = s >> 3, kc = (s & 7) * 8;
                pf[4 + i] = *(const uint4*)(Vtg + ((size_t)(b * 128 + ch) * MMK + k0n + kc));
            }
        }

        // ---- S^T = K . Q^T : D[key][qrow=l15] ----
        v4f s[4];
        #pragma unroll
        for (int kg = 0; kg < 4; ++kg) {
            v8bf kf[4];
            #pragma unroll
            for (int kk = 0; kk < 4; ++kk)
                kf[kk] = *(const v8bf*)(Ks + (kg * 16 + l15) * KS_STR + kk * 32 + quad * 8);
            v4f a; a[0] = 0.f; a[1] = 0.f; a[2] = 0.f; a[3] = 0.f;
            #pragma unroll
            for (int kk = 0; kk < 4; ++kk)
                a = MFMA16(kf[kk], qf[kk], a, 0, 0, 0);
            s[kg] = a;
        }

        // ---- online softmax (scalar state per lane; qrow = l15) ----
        {
            float cm = -1e30f;
            #pragma unroll
            for (int kg = 0; kg < 4; ++kg)
                #pragma unroll
                for (int r = 0; r < 4; ++r) cm = fmaxf(cm, s[kg][r]);
            cm = fmaxf(cm, __shfl_xor(cm, 16));
            cm = fmaxf(cm, __shfl_xor(cm, 32));
            const float nm = fmaxf(rm, cm);
            const float al = __expf(rm - nm);
            rm = nm;
            float cs = 0.f;
            #pragma unroll
            for (int kg = 0; kg < 4; ++kg)
                #pragma unroll
                for (int r = 0; r < 4; ++r) {
                    const float p = __expf(s[kg][r] - nm);
                    s[kg][r] = p; cs += p;
                }
            cs += __shfl_xor(cs, 16);
            cs += __shfl_xor(cs, 32);
            rl = rl * al + cs;
            #pragma unroll
            for (int cg = 0; cg < 8; ++cg)
                #pragma unroll
                for (int r = 0; r < 4; ++r) of[cg][r] *= al;
            #pragma unroll
            for (int kg = 0; kg < 4; ++kg) {
                union { __bf16 h[4]; uint2 u; } pk;
                #pragma unroll
                for (int r = 0; r < 4; ++r) pk.h[r] = (__bf16)s[kg][r];
                *(uint2*)(Pw + kg * 16 + quad * 4) = pk.u;
            }
        }

        // ---- O^T += Vt . P : D[ch][qrow=l15] ----
        #pragma unroll
        for (int kg2 = 0; kg2 < 2; ++kg2) {
            v8bf pfr = *(const v8bf*)(Pw + kg2 * 32 + quad * 8);
            #pragma unroll
            for (int cg = 0; cg < 8; ++cg) {
                v8bf vf = *(const v8bf*)(Vts + (cg * 16 + l15) * VT_STR + kg2 * 32 + quad * 8);
                of[cg] = MFMA16(vf, pfr, of[cg], 0, 0, 0);
            }
        }

        // ---- stage next chunk ----
        if (j < 15) {
            __syncthreads();
            #pragma unroll
            for (int i = 0; i < 4; ++i) {
                const int s = i * 256 + tid, key = s >> 4, c16 = s & 15;
                *(uint4*)(Ks + key * KS_STR + c16 * 8) = pf[i];
            }
            #pragma unroll
            for (int i = 0; i < 4; ++i) {
                const int s = i * 256 + tid, ch = s >> 3, kc = (s & 7) * 8;
                *(uint4*)(Vts + ch * VT_STR + kc) = pf[4 + i];
            }
            __syncthreads();
        }
    }

    // ---- epilogue: out = x + O/l ----
    {
        const float inv = 1.0f / rl;
        const int n = n0 + wave * 16 + l15;
        #pragma unroll
        for (int cg = 0; cg < 8; ++cg)
            #pragma unroll
            for (int r = 0; r < 4; ++r) {
                const int ch = cg * 16 + quad * 4 + r;
                const size_t gi = (size_t)(b * 128 + ch) * NN + n;
                out[gi] = x[gi] + of[cg][r] * inv;
            }
    }
}

extern "C" void kernel_launch(void* const* d_in, const int* in_sizes, int n_in,
                              void* d_out, int out_size, void* d_ws, size_t ws_size,
                              hipStream_t stream) {
    const float* x  = (const float*)d_in[0];
    const float* y  = (const float*)d_in[1];
    const float* Wq = (const float*)d_in[2];
    const float* bq = (const float*)d_in[3];
    const float* Wk = (const float*)d_in[4];
    const float* bk = (const float*)d_in[5];
    const float* Wv = (const float*)d_in[6];
    const float* bv = (const float*)d_in[7];
    float* out = (float*)d_out;

    __bf16* Qg  = (__bf16*)d_ws;                        // 8 MB
    __bf16* Kg  = Qg + (size_t)BB * NN * CCH;           // 2 MB
    __bf16* Vtg = Kg + (size_t)BB * MMK * CCH;          // 2 MB

    proj<<<384, 256, 0, stream>>>(x, y, Wq, bq, Wk, bk, Wv, bv, Qg, Kg, Vtg);
    attn<<<BB * (NN / 64), 256, 0, stream>>>(x, Qg, Kg, Vtg, out);
}

// Round 4
// 147.861 us; speedup vs baseline: 14.5521x; 1.2316x over previous
//
#include <hip/hip_runtime.h>

#define BB 8
#define NN 4096
#define MMK 1024

typedef __bf16 v8bf __attribute__((ext_vector_type(8)));
typedef float v4f __attribute__((ext_vector_type(4)));
typedef float v16f __attribute__((ext_vector_type(16)));
#define MFMA16 __builtin_amdgcn_mfma_f32_16x16x32_bf16
#define MFMA32 __builtin_amdgcn_mfma_f32_32x32x16_bf16

static __device__ __forceinline__ unsigned pkbf(float a, float b) {
    union { __bf16 h[2]; unsigned u; } o;
    o.h[0] = (__bf16)a; o.h[1] = (__bf16)b;
    return o.u;
}

// ---------------- Kernel 1: projections via MFMA, OUTPUT IN FRAG ORDER -------
// Frag layouts (16B chunk per lane):
//  Qfr chunk = ((b*128 + qt)*8 + s)*64 + lane   lane=(h*32+r): Q[q=qt*32+r][c=s*16+h*8+j]
//  Kfr chunk = ((b*32  + kt)*8 + s)*64 + lane   : K[key=kt*32+r][c=s*16+h*8+j]
//  Vfr chunk = (((b*32 + kt)*4 + cg)*2 + t)*64 + lane : Vt[ch=cg*32+r][key=kt*32+t*16+h*8+j]
__global__ __launch_bounds__(256, 1) void proj(
    const float* __restrict__ x, const float* __restrict__ y,
    const float* __restrict__ Wq, const float* __restrict__ bq,
    const float* __restrict__ Wk, const float* __restrict__ bk,
    const float* __restrict__ Wv, const float* __restrict__ bv,
    __bf16* __restrict__ Qfr, __bf16* __restrict__ Kfr, __bf16* __restrict__ Vfr)
{
    __shared__ __align__(16) __bf16 xt[128 * 132];
    __shared__ float bsh[128];

    const int tid = threadIdx.x;
    const int wave = tid >> 6, lane = tid & 63, l15 = lane & 15, quad = lane >> 4;
    const int bid = blockIdx.x;

    int job, b, t0, stride;
    const float *in, *W, *bias;
    if (bid < 256)      { job = 0; b = bid >> 5;         t0 = (bid & 31) * 128;        in = x; stride = NN;  W = Wq; bias = bq; }
    else if (bid < 320) { job = 1; b = (bid - 256) >> 3; t0 = ((bid - 256) & 7) * 128; in = y; stride = MMK; W = Wk; bias = bk; }
    else                { job = 2; b = (bid - 320) >> 3; t0 = ((bid - 320) & 7) * 128; in = y; stride = MMK; W = Wv; bias = bv; }

    #pragma unroll
    for (int i = 0; i < 16; ++i) {
        const int s = i * 256 + tid;
        const int c = s >> 5, c4 = s & 31;
        float4 v = *(const float4*)(in + (size_t)(b * 128 + c) * stride + t0 + c4 * 4);
        union { __bf16 h[4]; uint2 u; } o;
        o.h[0] = (__bf16)v.x; o.h[1] = (__bf16)v.y; o.h[2] = (__bf16)v.z; o.h[3] = (__bf16)v.w;
        *(uint2*)(xt + c * 132 + c4 * 4) = o.u;
    }
    if (tid < 128) bsh[tid] = bias[tid];
    __syncthreads();

    v8bf xf[2][4];
    #pragma unroll
    for (int tg2 = 0; tg2 < 2; ++tg2) {
        const int tok = (wave * 2 + tg2) * 16 + l15;
        #pragma unroll
        for (int cg = 0; cg < 4; ++cg) {
            union { __bf16 h[8]; v8bf v; } u;
            #pragma unroll
            for (int jj = 0; jj < 8; ++jj)
                u.h[jj] = xt[(cg * 32 + quad * 8 + jj) * 132 + tok];
            xf[tg2][cg] = u.v;
        }
    }

    const float scale = (job == 0) ? 0.0883883476483184f : 1.0f;  // 1/sqrt(128)

    for (int dg = 0; dg < 8; ++dg) {
        v8bf wf[4];
        #pragma unroll
        for (int cg = 0; cg < 4; ++cg) {
            const float* wp = W + (size_t)(dg * 16 + l15) * 128 + cg * 32 + quad * 8;
            float4 a = *(const float4*)wp;
            float4 c2 = *(const float4*)(wp + 4);
            union { __bf16 h[8]; v8bf v; } u;
            u.h[0] = (__bf16)a.x;  u.h[1] = (__bf16)a.y;  u.h[2] = (__bf16)a.z;  u.h[3] = (__bf16)a.w;
            u.h[4] = (__bf16)c2.x; u.h[5] = (__bf16)c2.y; u.h[6] = (__bf16)c2.z; u.h[7] = (__bf16)c2.w;
            wf[cg] = u.v;
        }
        float bz[4];
        #pragma unroll
        for (int r = 0; r < 4; ++r) bz[r] = bsh[dg * 16 + quad * 4 + r];

        #pragma unroll
        for (int tg2 = 0; tg2 < 2; ++tg2) {
            v4f acc;
            #pragma unroll
            for (int r = 0; r < 4; ++r) acc[r] = bz[r];
            #pragma unroll
            for (int cg = 0; cg < 4; ++cg)
                acc = MFMA16(wf[cg], xf[tg2][cg], acc, 0, 0, 0);
            #pragma unroll
            for (int r = 0; r < 4; ++r) acc[r] *= scale;

            const int tok = t0 + (wave * 2 + tg2) * 16 + l15;   // token within batch
            // d0 = dg*16 + quad*4  (4 consecutive output channels in acc[0..3])
            if (job <= 1) {
                __bf16* Out = (job == 0) ? Qfr : Kfr;
                const int tiles = (job == 0) ? 128 : 32;
                const size_t ci = ((size_t)(b * tiles + (tok >> 5)) * 8 + dg) * 64
                                  + (quad >> 1) * 32 + (tok & 31);
                union { __bf16 h[4]; uint2 u; } o4;
                #pragma unroll
                for (int r = 0; r < 4; ++r) o4.h[r] = (__bf16)acc[r];
                *(uint2*)((char*)Out + ci * 16 + (quad & 1) * 8) = o4.u;
            } else {
                #pragma unroll
                for (int r = 0; r < 4; ++r) {
                    const int d = dg * 16 + quad * 4 + r;
                    const size_t ci = (((size_t)(b * 32 + (tok >> 5)) * 4 + (d >> 5)) * 2
                                       + ((tok >> 4) & 1)) * 64
                                      + ((tok >> 3) & 1) * 32 + (d & 31);
                    Vfr[ci * 8 + (tok & 7)] = (__bf16)acc[r];
                }
            }
        }
    }
}

// ---------------- Kernel 2: barrier-free wave-split-K flash attention --------
// 1024 blocks x 128 thr (2 waves). Block: one 32-row q-tile; wave w owns keys
// w*512..w*512+511 (16 chunks of 32). All frag loads are coalesced 1KB b128.
__global__ __launch_bounds__(128, 2) void attn(
    const float* __restrict__ x, const __bf16* __restrict__ Qfr,
    const __bf16* __restrict__ Kfr, const __bf16* __restrict__ Vfr,
    float* __restrict__ out)
{
    __shared__ float Ob[2][2048];         // 16 KB: cross-wave O exchange
    __shared__ float combM[2][32], combL[2][32];

    const int tid = threadIdx.x;
    const int wave = tid >> 6, lane = tid & 63, r31 = lane & 31, h = lane >> 5;
    const int b = blockIdx.x >> 7;
    const int qt = blockIdx.x & 127;      // 32-row q-tile index within batch

    const v8bf* Qc = (const v8bf*)Qfr + (size_t)(b * 128 + qt) * 8 * 64;
    const v8bf* Kc = (const v8bf*)Kfr + (size_t)(b * 32 + wave * 16) * 8 * 64;
    const v8bf* Vc = (const v8bf*)Vfr + (size_t)(b * 32 + wave * 16) * 8 * 64;

    v8bf qf[8];
    #pragma unroll
    for (int s = 0; s < 8; ++s) qf[s] = Qc[s * 64 + lane];

    v16f o[4];
    #pragma unroll
    for (int cg = 0; cg < 4; ++cg)
        #pragma unroll
        for (int r = 0; r < 16; ++r) o[cg][r] = 0.f;
    float m = -1e30f, l = 0.f;

    for (int j = 0; j < 16; ++j) {
        // ---- S = K_chunk . Q^T : D[key][q], 32x32 ----
        v8bf kf[8];
        #pragma unroll
        for (int s = 0; s < 8; ++s) kf[s] = Kc[(j * 8 + s) * 64 + lane];
        v16f S;
        #pragma unroll
        for (int r = 0; r < 16; ++r) S[r] = 0.f;
        #pragma unroll
        for (int s = 0; s < 8; ++s) S = MFMA32(kf[s], qf[s], S, 0, 0, 0);

        // ---- online softmax: lane state covers q = r31 (dup across h) ----
        float c0 = fmaxf(fmaxf(S[0], S[1]), fmaxf(S[2], S[3]));
        float c1 = fmaxf(fmaxf(S[4], S[5]), fmaxf(S[6], S[7]));
        float c2 = fmaxf(fmaxf(S[8], S[9]), fmaxf(S[10], S[11]));
        float c3 = fmaxf(fmaxf(S[12], S[13]), fmaxf(S[14], S[15]));
        float cm = fmaxf(fmaxf(c0, c1), fmaxf(c2, c3));
        cm = fmaxf(cm, __shfl_xor(cm, 32));
        const float nm = fmaxf(m, cm);
        const float al = __expf(m - nm);
        m = nm;
        float p[16], cs = 0.f;
        #pragma unroll
        for (int r = 0; r < 16; ++r) { p[r] = __expf(S[r] - nm); cs += p[r]; }
        cs += __shfl_xor(cs, 32);
        l = l * al + cs;
        #pragma unroll
        for (int cg = 0; cg < 4; ++cg)
            #pragma unroll
            for (int r = 0; r < 16; ++r) o[cg][r] *= al;

        // ---- P: D-layout -> B-frag layout via shfl_xor(32), in registers ----
        v8bf pfr[2];
        #pragma unroll
        for (int t = 0; t < 2; ++t) {
            const int e = t * 8;
            const unsigned a0 = pkbf(p[e + 0], p[e + 1]);
            const unsigned a1 = pkbf(p[e + 2], p[e + 3]);
            const unsigned b0 = pkbf(p[e + 4], p[e + 5]);
            const unsigned b1 = pkbf(p[e + 6], p[e + 7]);
            const unsigned s0 = h ? a0 : b0;
            const unsigned s1 = h ? a1 : b1;
            const unsigned r0 = __shfl_xor(s0, 32);
            const unsigned r1 = __shfl_xor(s1, 32);
            union { unsigned u[4]; v8bf v; } fr;
            fr.u[0] = h ? r0 : a0;
            fr.u[1] = h ? r1 : a1;
            fr.u[2] = h ? b0 : r0;
            fr.u[3] = h ? b1 : r1;
            pfr[t] = fr.v;
        }

        // ---- O^T += Vt . P : D[ch][q] ----
        #pragma unroll
        for (int cg = 0; cg < 4; ++cg) {
            #pragma unroll
            for (int t = 0; t < 2; ++t) {
                v8bf vf = Vc[((j * 4 + cg) * 2 + t) * 64 + lane];
                o[cg] = MFMA32(vf, pfr[t], o[cg], 0, 0, 0);
            }
        }
    }

    // ---- cross-wave combine (split-K merge) ----
    if (h == 0) { combM[wave][r31] = m; combL[wave][r31] = l; }
    __syncthreads();
    const float m0 = combM[0][r31], m1 = combM[1][r31];
    const float l0 = combL[0][r31], l1 = combL[1][r31];
    const float ms = fmaxf(m0, m1);
    const float f0 = __expf(m0 - ms), f1 = __expf(m1 - ms);
    const float inv = 1.0f / (l0 * f0 + l1 * f1);
    const float fw = wave ? f1 : f0;

    // wave w exports its o for the OTHER wave's ch-half, scaled by fw
    #pragma unroll
    for (int cgL = 0; cgL < 2; ++cgL) {
        const int cgg = 2 * (1 - wave) + cgL;
        #pragma unroll
        for (int r = 0; r < 16; ++r)
            Ob[1 - wave][(cgL * 16 + r) * 64 + lane] = o[cgg][r] * fw;
    }
    __syncthreads();

    // combine own ch-half, add residual, store (full 128B lines per store)
    #pragma unroll
    for (int cgL = 0; cgL < 2; ++cgL) {
        const int cgg = 2 * wave + cgL;
        #pragma unroll
        for (int r = 0; r < 16; ++r) {
            const float val = (o[cgg][r] * fw + Ob[wave][(cgL * 16 + r) * 64 + lane]) * inv;
            const int ch = cgg * 32 + (r & 3) + 8 * (r >> 2) + 4 * h;
            const size_t gi = (size_t)(b * 128 + ch) * NN + qt * 32 + r31;
            out[gi] = x[gi] + val;
        }
    }
}

extern "C" void kernel_launch(void* const* d_in, const int* in_sizes, int n_in,
                              void* d_out, int out_size, void* d_ws, size_t ws_size,
                              hipStream_t stream) {
    const float* x  = (const float*)d_in[0];
    const float* y  = (const float*)d_in[1];
    const float* Wq = (const float*)d_in[2];
    const float* bq = (const float*)d_in[3];
    const float* Wk = (const float*)d_in[4];
    const float* bk = (const float*)d_in[5];
    const float* Wv = (const float*)d_in[6];
    const float* bv = (const float*)d_in[7];
    float* out = (float*)d_out;

    __bf16* Qfr = (__bf16*)d_ws;                        // 8 MB
    __bf16* Kfr = Qfr + (size_t)BB * NN * 128;          // 2 MB
    __bf16* Vfr = Kfr + (size_t)BB * MMK * 128;         // 2 MB

    proj<<<384, 256, 0, stream>>>(x, y, Wq, bq, Wk, bk, Wv, bv, Qfr, Kfr, Vfr);
    attn<<<BB * (NN / 32), 128, 0, stream>>>(x, Qfr, Kfr, Vfr, out);
}